// Round 5
// baseline (3369.365 us; speedup 1.0000x reference)
//
#include <hip/hip_runtime.h>

#define TSTEPS 2048
#define NENV   256
#define HID    128
#define EPB    16                 // envs per block (= MFMA M/N)
#define NBLK   (NENV / EPB)       // 16 blocks for the scan
#define NTHREADS 512              // 8 waves; wave w owns h-dims [16w,16w+16)

// gi layout (transposed + gate-interleaved):
//   [t][eb][env 16][jg 32][gate 3][4 j] fp32
// per-lane read = 3 contiguous floatx4 (48B) at one base + imm offsets.
#define GI_EB_STRIDE (EPB * HID * 3)              // 6144 elems per (t, eb)
#define GI_T_STRIDE  (NBLK * GI_EB_STRIDE)        // 98304 elems
#define GI_BYTES   ((size_t)TSTEPS * GI_T_STRIDE * sizeof(float))   // 805 MB

#define LOG2E 1.4426950408889634f

typedef float          floatx4  __attribute__((ext_vector_type(4)));
typedef __bf16         bf16x8   __attribute__((ext_vector_type(8)));
typedef unsigned short ushortx8 __attribute__((ext_vector_type(8)));
typedef unsigned int   uintx4   __attribute__((ext_vector_type(4)));
typedef unsigned int   uintx2   __attribute__((ext_vector_type(2)));

// fp32 -> bf16 round-to-nearest-even (scalar fallback)
__device__ __forceinline__ unsigned short f2bf(float f) {
    unsigned u = __float_as_uint(f);
    u += 0x7FFFu + ((u >> 16) & 1u);
    return (unsigned short)(u >> 16);
}

// packed fp32x2 -> bf16x2 (gfx950 v_cvt_pk_bf16_f32 when available)
__device__ __forceinline__ unsigned cvt_pk_bf16(float a, float b) {
#if __has_builtin(__builtin_amdgcn_cvt_pk_bf16_f32)
    typedef __bf16 bf16x2 __attribute__((ext_vector_type(2)));
    bf16x2 r = __builtin_amdgcn_cvt_pk_bf16_f32(a, b);
    return __builtin_bit_cast(unsigned, r);
#else
    return (unsigned)f2bf(a) | ((unsigned)f2bf(b) << 16);
#endif
}

__device__ __forceinline__ bf16x8 pack8(floatx4 a, floatx4 b) {
    uintx4 u;
    u[0] = cvt_pk_bf16(a[0], a[1]);
    u[1] = cvt_pk_bf16(a[2], a[3]);
    u[2] = cvt_pk_bf16(b[0], b[1]);
    u[3] = cvt_pk_bf16(b[2], b[3]);
    return __builtin_bit_cast(bf16x8, u);
}

__device__ __forceinline__ float fast_rcp(float x) {
#if __has_builtin(__builtin_amdgcn_rcpf)
    return __builtin_amdgcn_rcpf(x);
#else
    return 1.0f / x;
#endif
}
// raw 2^x (inputs are pre-scaled by +/-log2e at weight-pack time)
__device__ __forceinline__ float exp2_fast(float x) {
#if __has_builtin(__builtin_amdgcn_exp2f)
    return __builtin_amdgcn_exp2f(x);
#else
    float r; asm("v_exp_f32 %0, %1" : "=v"(r) : "v"(x)); return r;
#endif
}
// legacy helpers for the fused fallback kernel
__device__ __forceinline__ float sigm(float x) {
    return fast_rcp(1.0f + __expf(-x));
}
__device__ __forceinline__ float tanh_fast(float x) {
    return 1.0f - 2.0f * fast_rcp(1.0f + __expf(2.0f * x));
}

// ---------------------------------------------------------------------------
// Phase 1: gi (transposed, pre-scaled, b_hh[r,z] folded in).
//   gate r,z:  gi = -log2e * (x.W_ih + b_ih + b_hh)
//   gate n:    gi =  2log2e * (x.W_ih + b_ih)
// Grid: 2048 blocks = (tc 0..127) x (eb 0..15), 512 threads.
// mfma(W, x) -> C row = j, col = env: lane holds 4 consecutive j for one env.
// ---------------------------------------------------------------------------
__global__ __launch_bounds__(NTHREADS, 2)
void gi_gemm(const float* __restrict__ x,
             const float* __restrict__ w_ih,
             const float* __restrict__ b_ih,
             const float* __restrict__ b_hh,
             float* __restrict__ gi)
{
    const int tid  = threadIdx.x;
    const int wv   = tid >> 6;
    const int lane = tid & 63;
    const int quad = lane >> 4;
    const int l15  = lane & 15;
    const int eb   = blockIdx.x & 15;      // env group
    const int tc   = blockIdx.x >> 4;      // t chunk (16 steps)
    const int j    = wv * 16 + l15;        // weight row for A-frag
    const int jb   = wv * 16 + quad * 4;   // C-row base (4 consecutive j)

    const float gscale[3] = { -LOG2E, -LOG2E, 2.0f * LOG2E };

    // A-frags: w_ih rows (this wave's 16 j's), all 3 gates, pre-scaled
    bf16x8 bI[3][4];
#pragma unroll
    for (int q = 0; q < 3; ++q) {
        const int col = q * HID + j;
        const float s = gscale[q];
#pragma unroll
        for (int kk = 0; kk < 4; ++kk) {
            const int kb = kk * 32 + quad * 8;
            floatx4 f0 = *(const floatx4*)(w_ih + col * HID + kb);
            floatx4 f1 = *(const floatx4*)(w_ih + col * HID + kb + 4);
            bI[q][kk] = pack8(f0 * s, f1 * s);
        }
    }
    // per-reg biases (C rows = j => bias varies across acc regs)
    floatx4 biasv[3];
    {
        floatx4 bi0 = *(const floatx4*)(b_ih + jb);
        floatx4 bh0 = *(const floatx4*)(b_hh + jb);
        floatx4 bi1 = *(const floatx4*)(b_ih + HID + jb);
        floatx4 bh1 = *(const floatx4*)(b_hh + HID + jb);
        floatx4 bi2 = *(const floatx4*)(b_ih + 2 * HID + jb);
        biasv[0] = (bi0 + bh0) * (-LOG2E);
        biasv[1] = (bi1 + bh1) * (-LOG2E);
        biasv[2] = bi2 * (2.0f * LOG2E);
    }

    for (int tt = 0; tt < 16; ++tt) {
        const int t = tc * 16 + tt;
        // B-frag: x cols = envs (16), lane col = env l15, k = kk*32+quad*8
        const float* xr = x + (size_t)(t * NENV + eb * EPB + l15) * HID;
        bf16x8 ax[4];
#pragma unroll
        for (int kk = 0; kk < 4; ++kk) {
            const int kb = kk * 32 + quad * 8;
            floatx4 f0 = *(const floatx4*)(xr + kb);
            floatx4 f1 = *(const floatx4*)(xr + kb + 4);
            ax[kk] = pack8(f0, f1);
        }
        floatx4 acc[3];
#pragma unroll
        for (int q = 0; q < 3; ++q) acc[q] = biasv[q];
#pragma unroll
        for (int kk = 0; kk < 4; ++kk) {
            acc[0] = __builtin_amdgcn_mfma_f32_16x16x32_bf16(bI[0][kk], ax[kk], acc[0], 0, 0, 0);
            acc[1] = __builtin_amdgcn_mfma_f32_16x16x32_bf16(bI[1][kk], ax[kk], acc[1], 0, 0, 0);
            acc[2] = __builtin_amdgcn_mfma_f32_16x16x32_bf16(bI[2][kk], ax[kk], acc[2], 0, 0, 0);
        }
        // store: lane = (env=l15, jg=4wv+quad): 3 contiguous floatx4 (48B)
        float* dst = gi + (size_t)t * GI_T_STRIDE + eb * GI_EB_STRIDE
                        + l15 * (HID * 3) + (4 * wv + quad) * 12;
        *(floatx4*)(dst)     = acc[0];
        *(floatx4*)(dst + 4) = acc[1];
        *(floatx4*)(dst + 8) = acc[2];
    }
}

// ---------------------------------------------------------------------------
// Phase 2: sequential scan, h-side only. 16 blocks x 512 threads.
// mfma(W_hh, h) -> C row = j, col = env: lane owns env=l15, j = jb..jb+3.
// Vectorized epilogue: 1 dwordx4 out-store, 1 ds_write_b64 h-store.
// Raw s_barrier + lgkmcnt-only fence keeps global traffic in flight.
// ---------------------------------------------------------------------------
__global__ __launch_bounds__(NTHREADS, 2)
void gru_scan(const float* __restrict__ gi,
              const float* __restrict__ h0,
              const float* __restrict__ masks,
              const float* __restrict__ w_hh,
              const float* __restrict__ b_hh,
              float* __restrict__ out)
{
    __shared__ unsigned short hbuf[2][EPB][136];   // rows = env, cols = j (+8 pad)

    const int tid  = threadIdx.x;
    const int wv   = tid >> 6;
    const int lane = tid & 63;
    const int quad = lane >> 4;
    const int l15  = lane & 15;
    const int envbase = blockIdx.x * EPB;
    const int j  = wv * 16 + l15;          // weight row for A-frag
    const int jb = wv * 16 + quad * 4;     // C-row base (4 consecutive j)

    const float gscale[3] = { -LOG2E, -LOG2E, 2.0f * LOG2E };

    // A-frags: w_hh rows, pre-scaled
    bf16x8 bH[3][4];
#pragma unroll
    for (int q = 0; q < 3; ++q) {
        const int col = q * HID + j;
        const float s = gscale[q];
#pragma unroll
        for (int kk = 0; kk < 4; ++kk) {
            const int kb = kk * 32 + quad * 8;
            floatx4 g0 = *(const floatx4*)(w_hh + col * HID + kb);
            floatx4 g1 = *(const floatx4*)(w_hh + col * HID + kb + 4);
            bH[q][kk] = pack8(g0 * s, g1 * s);
        }
    }
    // n-gate hidden bias (inside the r-product), pre-scaled, per-reg j
    const floatx4 biasNHv = (*(const floatx4*)(b_hh + 2 * HID + jb)) * (2.0f * LOG2E);

    // init h (apply mask_0): lane owns env=l15, j=jb..jb+3
    float hC[4];
    {
        floatx4 h0v = *(const floatx4*)(h0 + (size_t)(envbase + l15) * HID + jb);
        float m0 = masks[envbase + l15];
#pragma unroll
        for (int i = 0; i < 4; ++i) hC[i] = h0v[i] * m0;
        uintx2 w; w[0] = cvt_pk_bf16(hC[0], hC[1]); w[1] = cvt_pk_bf16(hC[2], hC[3]);
        *(uintx2*)&hbuf[0][l15][jb] = w;
    }

    // gi base for this lane (gate-interleaved layout)
    const float* gbase = gi + (size_t)blockIdx.x * GI_EB_STRIDE
                            + l15 * (HID * 3) + (4 * wv + quad) * 12;

    // depth-2 software pipeline: gA/gB = gi[t], gi[t+1]; mA/mB = mask(t+1), mask(t+2)
    floatx4 gA[3], gB[3];
#pragma unroll
    for (int g = 0; g < 3; ++g) {
        gA[g] = *(const floatx4*)(gbase + g * 4);
        gB[g] = *(const floatx4*)(gbase + GI_T_STRIDE + g * 4);
    }
    float mA = masks[(size_t)1 * NENV + envbase + l15];
    float mB = masks[(size_t)2 * NENV + envbase + l15];

    float* const outs = out;
    float* const hfin = out + (size_t)TSTEPS * NENV * HID;

    auto step = [&](int t, int p, floatx4 (&gc)[3], float& mreg) {
        // hbuf[p^1] writes must be visible to all waves; LDS-only drain,
        // global loads/stores stay outstanding across the barrier.
        asm volatile("s_waitcnt lgkmcnt(0)" ::: "memory");
        __builtin_amdgcn_s_barrier();
        __builtin_amdgcn_sched_barrier(0);

        // B-frags for h from LDS (lane col = env l15, k contiguous)
        bf16x8 ah[4];
#pragma unroll
        for (int kk = 0; kk < 4; ++kk) {
            ah[kk] = __builtin_bit_cast(bf16x8,
                *(const ushortx8*)&hbuf[p][l15][kk * 32 + quad * 8]);
        }

        // consume gc (biases already folded/scaled at gemm time)
        floatx4 accR  = gc[0];
        floatx4 accZ  = gc[1];
        floatx4 gN    = gc[2];
        floatx4 accNH = biasNHv;

        // prefetch gi[t+2] into the same registers (~2 steps of slack)
        if (t + 2 < TSTEPS) {
            const float* gp = gbase + (size_t)(t + 2) * GI_T_STRIDE;
            gc[0] = *(const floatx4*)(gp);
            gc[1] = *(const floatx4*)(gp + 4);
            gc[2] = *(const floatx4*)(gp + 8);
        }
        // mask(t+1) for this step's epilogue; reload mreg with mask(t+3)
        float mn = mreg;
        mreg = (t + 3 < TSTEPS)
             ? masks[(size_t)(t + 3) * NENV + envbase + l15] : 1.0f;

#pragma unroll
        for (int kk = 0; kk < 4; ++kk) {
            accR  = __builtin_amdgcn_mfma_f32_16x16x32_bf16(bH[0][kk], ah[kk], accR,  0, 0, 0);
            accZ  = __builtin_amdgcn_mfma_f32_16x16x32_bf16(bH[1][kk], ah[kk], accZ,  0, 0, 0);
            accNH = __builtin_amdgcn_mfma_f32_16x16x32_bf16(bH[2][kk], ah[kk], accNH, 0, 0, 0);
        }

        floatx4 hv;
#pragma unroll
        for (int i = 0; i < 4; ++i) {
            // accR/accZ = -log2e*pre  => sigmoid = rcp(1+2^acc)
            float r    = fast_rcp(1.0f + exp2_fast(accR[i]));
            float z    = fast_rcp(1.0f + exp2_fast(accZ[i]));
            // gN/accNH = 2log2e*pre   => tanh = 1 - 2*rcp(1+2^in)
            float ti   = gN[i] + r * accNH[i];
            float n    = 1.0f - 2.0f * fast_rcp(1.0f + exp2_fast(ti));
            float hnew = n + z * (hC[i] - n);
            hv[i] = hnew;
            hC[i] = hnew * mn;
        }
        *(floatx4*)(outs + ((size_t)t * NENV + envbase + l15) * HID + jb) = hv;
        uintx2 w; w[0] = cvt_pk_bf16(hC[0], hC[1]); w[1] = cvt_pk_bf16(hC[2], hC[3]);
        *(uintx2*)&hbuf[p ^ 1][l15][jb] = w;
    };

    for (int t = 0; t < TSTEPS; t += 2) {
        step(t,     0, gA, mA);
        step(t + 1, 1, gB, mB);
    }
    // final state: mask(2048) forced to 1.0, so hC == h_{T-1}
    floatx4 hf; hf[0] = hC[0]; hf[1] = hC[1]; hf[2] = hC[2]; hf[3] = hC[3];
    *(floatx4*)(hfin + (size_t)(envbase + l15) * HID + jb) = hf;
}

// ---------------------------------------------------------------------------
// Fallback: round-1 fused kernel (used only if ws_size < GI_BYTES)
// ---------------------------------------------------------------------------
__global__ __launch_bounds__(NTHREADS, 2)
void gru_fused(const float* __restrict__ x,
               const float* __restrict__ h0,
               const float* __restrict__ masks,
               const float* __restrict__ w_ih,
               const float* __restrict__ w_hh,
               const float* __restrict__ b_ih,
               const float* __restrict__ b_hh,
               float* __restrict__ out)
{
    __shared__ unsigned short hbuf[2][EPB][136];

    const int tid  = threadIdx.x;
    const int wv   = tid >> 6;
    const int lane = tid & 63;
    const int quad = lane >> 4;
    const int l15  = lane & 15;
    const int envbase = blockIdx.x * EPB;
    const int j = wv * 16 + l15;

    bf16x8 bI[3][4], bH[3][4];
#pragma unroll
    for (int q = 0; q < 3; ++q) {
        const int col = q * HID + j;
#pragma unroll
        for (int kk = 0; kk < 4; ++kk) {
            const int kb = kk * 32 + quad * 8;
            floatx4 f0 = *(const floatx4*)(w_ih + col * HID + kb);
            floatx4 f1 = *(const floatx4*)(w_ih + col * HID + kb + 4);
            bI[q][kk] = pack8(f0, f1);
            floatx4 g0 = *(const floatx4*)(w_hh + col * HID + kb);
            floatx4 g1 = *(const floatx4*)(w_hh + col * HID + kb + 4);
            bH[q][kk] = pack8(g0, g1);
        }
    }

    const float biasR  = b_ih[j]           + b_hh[j];
    const float biasZ  = b_ih[HID + j]     + b_hh[HID + j];
    const float biasNI = b_ih[2 * HID + j];
    const float biasNH = b_hh[2 * HID + j];

    float hC[4];
    {
        floatx4 m0 = *(const floatx4*)(masks + envbase + quad * 4);
#pragma unroll
        for (int i = 0; i < 4; ++i) {
            const int e = quad * 4 + i;
            float h = h0[(envbase + e) * HID + j] * m0[i];
            hC[i] = h;
            hbuf[0][e][j] = f2bf(h);
        }
    }

    floatx4 xA[8], xB[8];
    {
        const float* xr = x + (size_t)(envbase + l15) * HID;
#pragma unroll
        for (int kk = 0; kk < 4; ++kk) {
            const int kb = kk * 32 + quad * 8;
            xA[2 * kk]     = *(const floatx4*)(xr + kb);
            xA[2 * kk + 1] = *(const floatx4*)(xr + kb + 4);
        }
    }

    float* const outs = out;
    float* const hfin = out + (size_t)TSTEPS * NENV * HID;

    auto step = [&](int t, int p, floatx4 (&xc)[8], floatx4 (&xn)[8]) {
        __syncthreads();
        bf16x8 ah[4];
#pragma unroll
        for (int kk = 0; kk < 4; ++kk) {
            ah[kk] = __builtin_bit_cast(bf16x8,
                *(const ushortx8*)&hbuf[p][l15][kk * 32 + quad * 8]);
        }
        bf16x8 ax[4];
#pragma unroll
        for (int kk = 0; kk < 4; ++kk) ax[kk] = pack8(xc[2 * kk], xc[2 * kk + 1]);

        if (t + 1 < TSTEPS) {
            const float* xr = x + (size_t)((t + 1) * NENV + envbase + l15) * HID;
#pragma unroll
            for (int kk = 0; kk < 4; ++kk) {
                const int kb = kk * 32 + quad * 8;
                xn[2 * kk]     = *(const floatx4*)(xr + kb);
                xn[2 * kk + 1] = *(const floatx4*)(xr + kb + 4);
            }
        }
        floatx4 mn;
        if (t + 1 < TSTEPS) {
            mn = *(const floatx4*)(masks + (size_t)(t + 1) * NENV + envbase + quad * 4);
        } else {
            mn[0] = mn[1] = mn[2] = mn[3] = 1.0f;
        }

        floatx4 accR  = {biasR,  biasR,  biasR,  biasR};
        floatx4 accZ  = {biasZ,  biasZ,  biasZ,  biasZ};
        floatx4 accNI = {biasNI, biasNI, biasNI, biasNI};
        floatx4 accNH = {biasNH, biasNH, biasNH, biasNH};
#pragma unroll
        for (int kk = 0; kk < 4; ++kk) {
            accR  = __builtin_amdgcn_mfma_f32_16x16x32_bf16(ax[kk], bI[0][kk], accR,  0, 0, 0);
            accR  = __builtin_amdgcn_mfma_f32_16x16x32_bf16(ah[kk], bH[0][kk], accR,  0, 0, 0);
            accZ  = __builtin_amdgcn_mfma_f32_16x16x32_bf16(ax[kk], bI[1][kk], accZ,  0, 0, 0);
            accZ  = __builtin_amdgcn_mfma_f32_16x16x32_bf16(ah[kk], bH[1][kk], accZ,  0, 0, 0);
            accNI = __builtin_amdgcn_mfma_f32_16x16x32_bf16(ax[kk], bI[2][kk], accNI, 0, 0, 0);
            accNH = __builtin_amdgcn_mfma_f32_16x16x32_bf16(ah[kk], bH[2][kk], accNH, 0, 0, 0);
        }

#pragma unroll
        for (int i = 0; i < 4; ++i) {
            const int e = quad * 4 + i;
            float r    = sigm(accR[i]);
            float z    = sigm(accZ[i]);
            float n    = tanh_fast(accNI[i] + r * accNH[i]);
            float hnew = n + z * (hC[i] - n);
            outs[((size_t)t * NENV + envbase + e) * HID + j] = hnew;
            if (t == TSTEPS - 1) hfin[(envbase + e) * HID + j] = hnew;
            float hm = hnew * mn[i];
            hC[i] = hm;
            hbuf[p ^ 1][e][j] = f2bf(hm);
        }
    };

    for (int t = 0; t < TSTEPS; t += 2) {
        step(t,     0, xA, xB);
        step(t + 1, 1, xB, xA);
    }
}

extern "C" void kernel_launch(void* const* d_in, const int* in_sizes, int n_in,
                              void* d_out, int out_size, void* d_ws, size_t ws_size,
                              hipStream_t stream) {
    const float* x    = (const float*)d_in[0];
    const float* h0   = (const float*)d_in[1];
    const float* mks  = (const float*)d_in[2];
    const float* w_ih = (const float*)d_in[3];
    const float* w_hh = (const float*)d_in[4];
    const float* b_ih = (const float*)d_in[5];
    const float* b_hh = (const float*)d_in[6];
    (void)in_sizes; (void)n_in; (void)out_size;

    if (ws_size >= GI_BYTES) {
        float* gi = (float*)d_ws;
        gi_gemm<<<dim3(128 * 16), dim3(NTHREADS), 0, stream>>>(x, w_ih, b_ih, b_hh, gi);
        gru_scan<<<dim3(NBLK), dim3(NTHREADS), 0, stream>>>(gi, h0, mks, w_hh, b_hh,
                                                            (float*)d_out);
    } else {
        gru_fused<<<dim3(NBLK), dim3(NTHREADS), 0, stream>>>(
            x, h0, mks, w_ih, w_hh, b_ih, b_hh, (float*)d_out);
    }
}

// Round 6
// 2384.665 us; speedup vs baseline: 1.4129x; 1.4129x over previous
//
#include <hip/hip_runtime.h>

#define TSTEPS 2048
#define NENV   256
#define HID    128
#define EPB    16                 // envs per block (= MFMA M/N)
#define NBLK   (NENV / EPB)       // 16 blocks for the scan
#define NTHREADS 512              // 8 waves; wave w owns h-dims [16w,16w+16)

// gi layout: [t][gate][eb][jq(32)=4*wv+quad][env(16)=l15][4 j] fp32.
// Per gate-load/store instruction a wave touches one CONTIGUOUS 1KB segment
// (lane(quad,l15) at wv*1024 + quad*256 + l15*16 bytes) -- wave-coalesced,
// while each lane still owns 4 consecutive j for one env (vector epilogue).
#define GI_EB_STRIDE (32 * EPB * 4)               // 2048 elems per (t,g,eb)
#define GI_G_STRIDE  (NBLK * GI_EB_STRIDE)        // 32768 elems
#define GI_T_STRIDE  (3 * GI_G_STRIDE)            // 98304 elems
#define GI_BYTES   ((size_t)TSTEPS * GI_T_STRIDE * sizeof(float))   // 805 MB

#define LOG2E 1.4426950408889634f

typedef float          floatx4  __attribute__((ext_vector_type(4)));
typedef __bf16         bf16x8   __attribute__((ext_vector_type(8)));
typedef unsigned short ushortx8 __attribute__((ext_vector_type(8)));
typedef unsigned int   uintx4   __attribute__((ext_vector_type(4)));
typedef unsigned int   uintx2   __attribute__((ext_vector_type(2)));

// fp32 -> bf16 round-to-nearest-even (scalar fallback)
__device__ __forceinline__ unsigned short f2bf(float f) {
    unsigned u = __float_as_uint(f);
    u += 0x7FFFu + ((u >> 16) & 1u);
    return (unsigned short)(u >> 16);
}

// packed fp32x2 -> bf16x2 (gfx950 v_cvt_pk_bf16_f32 when available)
__device__ __forceinline__ unsigned cvt_pk_bf16(float a, float b) {
#if __has_builtin(__builtin_amdgcn_cvt_pk_bf16_f32)
    typedef __bf16 bf16x2 __attribute__((ext_vector_type(2)));
    bf16x2 r = __builtin_amdgcn_cvt_pk_bf16_f32(a, b);
    return __builtin_bit_cast(unsigned, r);
#else
    return (unsigned)f2bf(a) | ((unsigned)f2bf(b) << 16);
#endif
}

__device__ __forceinline__ bf16x8 pack8(floatx4 a, floatx4 b) {
    uintx4 u;
    u[0] = cvt_pk_bf16(a[0], a[1]);
    u[1] = cvt_pk_bf16(a[2], a[3]);
    u[2] = cvt_pk_bf16(b[0], b[1]);
    u[3] = cvt_pk_bf16(b[2], b[3]);
    return __builtin_bit_cast(bf16x8, u);
}

__device__ __forceinline__ float fast_rcp(float x) {
#if __has_builtin(__builtin_amdgcn_rcpf)
    return __builtin_amdgcn_rcpf(x);
#else
    return 1.0f / x;
#endif
}
// raw 2^x (inputs are pre-scaled by +/-log2e at weight-pack time)
__device__ __forceinline__ float exp2_fast(float x) {
#if __has_builtin(__builtin_amdgcn_exp2f)
    return __builtin_amdgcn_exp2f(x);
#else
    float r; asm("v_exp_f32 %0, %1" : "=v"(r) : "v"(x)); return r;
#endif
}
// legacy helpers for the fused fallback kernel
__device__ __forceinline__ float sigm(float x) {
    return fast_rcp(1.0f + __expf(-x));
}
__device__ __forceinline__ float tanh_fast(float x) {
    return 1.0f - 2.0f * fast_rcp(1.0f + __expf(2.0f * x));
}

// ---------------------------------------------------------------------------
// Phase 1: gi (pre-scaled, b_hh[r,z] folded in).
//   gate r,z:  gi = -log2e * (x.W_ih + b_ih + b_hh)
//   gate n:    gi =  2log2e * (x.W_ih + b_ih)
// Grid: 2048 blocks = (tc 0..127) x (eb 0..15), 512 threads.
// mfma(W, x) -> C row = j, col = env: lane holds 4 consecutive j for one env.
// Store: one contiguous 1KB per wave per gate.
// ---------------------------------------------------------------------------
__global__ __launch_bounds__(NTHREADS, 2)
void gi_gemm(const float* __restrict__ x,
             const float* __restrict__ w_ih,
             const float* __restrict__ b_ih,
             const float* __restrict__ b_hh,
             float* __restrict__ gi)
{
    const int tid  = threadIdx.x;
    const int wv   = tid >> 6;
    const int lane = tid & 63;
    const int quad = lane >> 4;
    const int l15  = lane & 15;
    const int eb   = blockIdx.x & 15;      // env group
    const int tc   = blockIdx.x >> 4;      // t chunk (16 steps)
    const int j    = wv * 16 + l15;        // weight row for A-frag
    const int jb   = wv * 16 + quad * 4;   // C-row base (4 consecutive j)

    const float gscale[3] = { -LOG2E, -LOG2E, 2.0f * LOG2E };

    // A-frags: w_ih rows (this wave's 16 j's), all 3 gates, pre-scaled
    bf16x8 bI[3][4];
#pragma unroll
    for (int q = 0; q < 3; ++q) {
        const int col = q * HID + j;
        const float s = gscale[q];
#pragma unroll
        for (int kk = 0; kk < 4; ++kk) {
            const int kb = kk * 32 + quad * 8;
            floatx4 f0 = *(const floatx4*)(w_ih + col * HID + kb);
            floatx4 f1 = *(const floatx4*)(w_ih + col * HID + kb + 4);
            bI[q][kk] = pack8(f0 * s, f1 * s);
        }
    }
    // per-reg biases (C rows = j => bias varies across acc regs)
    floatx4 biasv[3];
    {
        floatx4 bi0 = *(const floatx4*)(b_ih + jb);
        floatx4 bh0 = *(const floatx4*)(b_hh + jb);
        floatx4 bi1 = *(const floatx4*)(b_ih + HID + jb);
        floatx4 bh1 = *(const floatx4*)(b_hh + HID + jb);
        floatx4 bi2 = *(const floatx4*)(b_ih + 2 * HID + jb);
        biasv[0] = (bi0 + bh0) * (-LOG2E);
        biasv[1] = (bi1 + bh1) * (-LOG2E);
        biasv[2] = bi2 * (2.0f * LOG2E);
    }

    // per-lane gi offset within a (t, gate) plane: contiguous 1KB per wave
    const int gioff = eb * GI_EB_STRIDE + (4 * wv + quad) * (EPB * 4) + l15 * 4;

    for (int tt = 0; tt < 16; ++tt) {
        const int t = tc * 16 + tt;
        // B-frag: x cols = envs (16), lane col = env l15, k = kk*32+quad*8
        const float* xr = x + (size_t)(t * NENV + eb * EPB + l15) * HID;
        bf16x8 ax[4];
#pragma unroll
        for (int kk = 0; kk < 4; ++kk) {
            const int kb = kk * 32 + quad * 8;
            floatx4 f0 = *(const floatx4*)(xr + kb);
            floatx4 f1 = *(const floatx4*)(xr + kb + 4);
            ax[kk] = pack8(f0, f1);
        }
        floatx4 acc[3];
#pragma unroll
        for (int q = 0; q < 3; ++q) acc[q] = biasv[q];
#pragma unroll
        for (int kk = 0; kk < 4; ++kk) {
            acc[0] = __builtin_amdgcn_mfma_f32_16x16x32_bf16(bI[0][kk], ax[kk], acc[0], 0, 0, 0);
            acc[1] = __builtin_amdgcn_mfma_f32_16x16x32_bf16(bI[1][kk], ax[kk], acc[1], 0, 0, 0);
            acc[2] = __builtin_amdgcn_mfma_f32_16x16x32_bf16(bI[2][kk], ax[kk], acc[2], 0, 0, 0);
        }
        float* dst = gi + (size_t)t * GI_T_STRIDE + gioff;
        *(floatx4*)(dst)                    = acc[0];
        *(floatx4*)(dst + GI_G_STRIDE)      = acc[1];
        *(floatx4*)(dst + 2 * GI_G_STRIDE)  = acc[2];
    }
}

// ---------------------------------------------------------------------------
// Phase 2: sequential scan, h-side only. 16 blocks x 512 threads.
// mfma(W_hh, h) -> C row = j, col = env: lane owns env=l15, j = jb..jb+3.
// Vectorized epilogue: 1 dwordx4 out-store, 1 ds_write_b64 h-store.
// gi loads: contiguous 1KB per wave per gate. Raw s_barrier + lgkmcnt-only
// fence keeps global traffic in flight across barriers.
// ---------------------------------------------------------------------------
__global__ __launch_bounds__(NTHREADS, 2)
void gru_scan(const float* __restrict__ gi,
              const float* __restrict__ h0,
              const float* __restrict__ masks,
              const float* __restrict__ w_hh,
              const float* __restrict__ b_hh,
              float* __restrict__ out)
{
    __shared__ unsigned short hbuf[2][EPB][136];   // rows = env, cols = j (+8 pad)

    const int tid  = threadIdx.x;
    const int wv   = tid >> 6;
    const int lane = tid & 63;
    const int quad = lane >> 4;
    const int l15  = lane & 15;
    const int envbase = blockIdx.x * EPB;
    const int j  = wv * 16 + l15;          // weight row for A-frag
    const int jb = wv * 16 + quad * 4;     // C-row base (4 consecutive j)

    const float gscale[3] = { -LOG2E, -LOG2E, 2.0f * LOG2E };

    // A-frags: w_hh rows, pre-scaled
    bf16x8 bH[3][4];
#pragma unroll
    for (int q = 0; q < 3; ++q) {
        const int col = q * HID + j;
        const float s = gscale[q];
#pragma unroll
        for (int kk = 0; kk < 4; ++kk) {
            const int kb = kk * 32 + quad * 8;
            floatx4 g0 = *(const floatx4*)(w_hh + col * HID + kb);
            floatx4 g1 = *(const floatx4*)(w_hh + col * HID + kb + 4);
            bH[q][kk] = pack8(g0 * s, g1 * s);
        }
    }
    // n-gate hidden bias (inside the r-product), pre-scaled, per-reg j
    const floatx4 biasNHv = (*(const floatx4*)(b_hh + 2 * HID + jb)) * (2.0f * LOG2E);

    // init h (apply mask_0): lane owns env=l15, j=jb..jb+3
    float hC[4];
    {
        floatx4 h0v = *(const floatx4*)(h0 + (size_t)(envbase + l15) * HID + jb);
        float m0 = masks[envbase + l15];
#pragma unroll
        for (int i = 0; i < 4; ++i) hC[i] = h0v[i] * m0;
        uintx2 w; w[0] = cvt_pk_bf16(hC[0], hC[1]); w[1] = cvt_pk_bf16(hC[2], hC[3]);
        *(uintx2*)&hbuf[0][l15][jb] = w;
    }

    // gi base for this lane: wave-contiguous 1KB per gate-load
    const float* gbase = gi + (size_t)blockIdx.x * GI_EB_STRIDE
                            + (4 * wv + quad) * (EPB * 4) + l15 * 4;

    // depth-2 software pipeline: gA/gB = gi[t], gi[t+1]; mA/mB = mask(t+1), mask(t+2)
    floatx4 gA[3], gB[3];
#pragma unroll
    for (int g = 0; g < 3; ++g) {
        gA[g] = *(const floatx4*)(gbase + g * GI_G_STRIDE);
        gB[g] = *(const floatx4*)(gbase + GI_T_STRIDE + g * GI_G_STRIDE);
    }
    float mA = masks[(size_t)1 * NENV + envbase + l15];
    float mB = masks[(size_t)2 * NENV + envbase + l15];

    float* const outs = out;
    float* const hfin = out + (size_t)TSTEPS * NENV * HID;

    auto step = [&](int t, int p, floatx4 (&gc)[3], float& mreg) {
        // hbuf[p^1] writes must be visible to all waves; LDS-only drain,
        // global loads/stores stay outstanding across the barrier.
        asm volatile("s_waitcnt lgkmcnt(0)" ::: "memory");
        __builtin_amdgcn_s_barrier();
        __builtin_amdgcn_sched_barrier(0);

        // B-frags for h from LDS (lane col = env l15, k contiguous)
        bf16x8 ah[4];
#pragma unroll
        for (int kk = 0; kk < 4; ++kk) {
            ah[kk] = __builtin_bit_cast(bf16x8,
                *(const ushortx8*)&hbuf[p][l15][kk * 32 + quad * 8]);
        }

        // consume gc (biases already folded/scaled at gemm time)
        floatx4 accR  = gc[0];
        floatx4 accZ  = gc[1];
        floatx4 gN    = gc[2];
        floatx4 accNH = biasNHv;

        // prefetch gi[t+2] into the same registers (~2 steps of slack)
        if (t + 2 < TSTEPS) {
            const float* gp = gbase + (size_t)(t + 2) * GI_T_STRIDE;
            gc[0] = *(const floatx4*)(gp);
            gc[1] = *(const floatx4*)(gp + GI_G_STRIDE);
            gc[2] = *(const floatx4*)(gp + 2 * GI_G_STRIDE);
        }
        // mask(t+1) for this step's epilogue; reload mreg with mask(t+3)
        float mn = mreg;
        mreg = (t + 3 < TSTEPS)
             ? masks[(size_t)(t + 3) * NENV + envbase + l15] : 1.0f;

#pragma unroll
        for (int kk = 0; kk < 4; ++kk) {
            accR  = __builtin_amdgcn_mfma_f32_16x16x32_bf16(bH[0][kk], ah[kk], accR,  0, 0, 0);
            accZ  = __builtin_amdgcn_mfma_f32_16x16x32_bf16(bH[1][kk], ah[kk], accZ,  0, 0, 0);
            accNH = __builtin_amdgcn_mfma_f32_16x16x32_bf16(bH[2][kk], ah[kk], accNH, 0, 0, 0);
        }

        floatx4 hv;
#pragma unroll
        for (int i = 0; i < 4; ++i) {
            // accR/accZ = -log2e*pre  => sigmoid = rcp(1+2^acc)
            float r    = fast_rcp(1.0f + exp2_fast(accR[i]));
            float z    = fast_rcp(1.0f + exp2_fast(accZ[i]));
            // gN/accNH = 2log2e*pre   => tanh = 1 - 2*rcp(1+2^in)
            float ti   = gN[i] + r * accNH[i];
            float n    = 1.0f - 2.0f * fast_rcp(1.0f + exp2_fast(ti));
            float hnew = n + z * (hC[i] - n);
            hv[i] = hnew;
            hC[i] = hnew * mn;
        }
        *(floatx4*)(outs + ((size_t)t * NENV + envbase + l15) * HID + jb) = hv;
        uintx2 w; w[0] = cvt_pk_bf16(hC[0], hC[1]); w[1] = cvt_pk_bf16(hC[2], hC[3]);
        *(uintx2*)&hbuf[p ^ 1][l15][jb] = w;
    };

    for (int t = 0; t < TSTEPS; t += 2) {
        step(t,     0, gA, mA);
        step(t + 1, 1, gB, mB);
    }
    // final state: mask(2048) forced to 1.0, so hC == h_{T-1}
    floatx4 hf; hf[0] = hC[0]; hf[1] = hC[1]; hf[2] = hC[2]; hf[3] = hC[3];
    *(floatx4*)(hfin + (size_t)(envbase + l15) * HID + jb) = hf;
}

// ---------------------------------------------------------------------------
// Fallback: round-1 fused kernel (used only if ws_size < GI_BYTES)
// ---------------------------------------------------------------------------
__global__ __launch_bounds__(NTHREADS, 2)
void gru_fused(const float* __restrict__ x,
               const float* __restrict__ h0,
               const float* __restrict__ masks,
               const float* __restrict__ w_ih,
               const float* __restrict__ w_hh,
               const float* __restrict__ b_ih,
               const float* __restrict__ b_hh,
               float* __restrict__ out)
{
    __shared__ unsigned short hbuf[2][EPB][136];

    const int tid  = threadIdx.x;
    const int wv   = tid >> 6;
    const int lane = tid & 63;
    const int quad = lane >> 4;
    const int l15  = lane & 15;
    const int envbase = blockIdx.x * EPB;
    const int j = wv * 16 + l15;

    bf16x8 bI[3][4], bH[3][4];
#pragma unroll
    for (int q = 0; q < 3; ++q) {
        const int col = q * HID + j;
#pragma unroll
        for (int kk = 0; kk < 4; ++kk) {
            const int kb = kk * 32 + quad * 8;
            floatx4 f0 = *(const floatx4*)(w_ih + col * HID + kb);
            floatx4 f1 = *(const floatx4*)(w_ih + col * HID + kb + 4);
            bI[q][kk] = pack8(f0, f1);
            floatx4 g0 = *(const floatx4*)(w_hh + col * HID + kb);
            floatx4 g1 = *(const floatx4*)(w_hh + col * HID + kb + 4);
            bH[q][kk] = pack8(g0, g1);
        }
    }

    const float biasR  = b_ih[j]           + b_hh[j];
    const float biasZ  = b_ih[HID + j]     + b_hh[HID + j];
    const float biasNI = b_ih[2 * HID + j];
    const float biasNH = b_hh[2 * HID + j];

    float hC[4];
    {
        floatx4 m0 = *(const floatx4*)(masks + envbase + quad * 4);
#pragma unroll
        for (int i = 0; i < 4; ++i) {
            const int e = quad * 4 + i;
            float h = h0[(envbase + e) * HID + j] * m0[i];
            hC[i] = h;
            hbuf[0][e][j] = f2bf(h);
        }
    }

    floatx4 xA[8], xB[8];
    {
        const float* xr = x + (size_t)(envbase + l15) * HID;
#pragma unroll
        for (int kk = 0; kk < 4; ++kk) {
            const int kb = kk * 32 + quad * 8;
            xA[2 * kk]     = *(const floatx4*)(xr + kb);
            xA[2 * kk + 1] = *(const floatx4*)(xr + kb + 4);
        }
    }

    float* const outs = out;
    float* const hfin = out + (size_t)TSTEPS * NENV * HID;

    auto step = [&](int t, int p, floatx4 (&xc)[8], floatx4 (&xn)[8]) {
        __syncthreads();
        bf16x8 ah[4];
#pragma unroll
        for (int kk = 0; kk < 4; ++kk) {
            ah[kk] = __builtin_bit_cast(bf16x8,
                *(const ushortx8*)&hbuf[p][l15][kk * 32 + quad * 8]);
        }
        bf16x8 ax[4];
#pragma unroll
        for (int kk = 0; kk < 4; ++kk) ax[kk] = pack8(xc[2 * kk], xc[2 * kk + 1]);

        if (t + 1 < TSTEPS) {
            const float* xr = x + (size_t)((t + 1) * NENV + envbase + l15) * HID;
#pragma unroll
            for (int kk = 0; kk < 4; ++kk) {
                const int kb = kk * 32 + quad * 8;
                xn[2 * kk]     = *(const floatx4*)(xr + kb);
                xn[2 * kk + 1] = *(const floatx4*)(xr + kb + 4);
            }
        }
        floatx4 mn;
        if (t + 1 < TSTEPS) {
            mn = *(const floatx4*)(masks + (size_t)(t + 1) * NENV + envbase + quad * 4);
        } else {
            mn[0] = mn[1] = mn[2] = mn[3] = 1.0f;
        }

        floatx4 accR  = {biasR,  biasR,  biasR,  biasR};
        floatx4 accZ  = {biasZ,  biasZ,  biasZ,  biasZ};
        floatx4 accNI = {biasNI, biasNI, biasNI, biasNI};
        floatx4 accNH = {biasNH, biasNH, biasNH, biasNH};
#pragma unroll
        for (int kk = 0; kk < 4; ++kk) {
            accR  = __builtin_amdgcn_mfma_f32_16x16x32_bf16(ax[kk], bI[0][kk], accR,  0, 0, 0);
            accR  = __builtin_amdgcn_mfma_f32_16x16x32_bf16(ah[kk], bH[0][kk], accR,  0, 0, 0);
            accZ  = __builtin_amdgcn_mfma_f32_16x16x32_bf16(ax[kk], bI[1][kk], accZ,  0, 0, 0);
            accZ  = __builtin_amdgcn_mfma_f32_16x16x32_bf16(ah[kk], bH[1][kk], accZ,  0, 0, 0);
            accNI = __builtin_amdgcn_mfma_f32_16x16x32_bf16(ax[kk], bI[2][kk], accNI, 0, 0, 0);
            accNH = __builtin_amdgcn_mfma_f32_16x16x32_bf16(ah[kk], bH[2][kk], accNH, 0, 0, 0);
        }

#pragma unroll
        for (int i = 0; i < 4; ++i) {
            const int e = quad * 4 + i;
            float r    = sigm(accR[i]);
            float z    = sigm(accZ[i]);
            float n    = tanh_fast(accNI[i] + r * accNH[i]);
            float hnew = n + z * (hC[i] - n);
            outs[((size_t)t * NENV + envbase + e) * HID + j] = hnew;
            if (t == TSTEPS - 1) hfin[(envbase + e) * HID + j] = hnew;
            float hm = hnew * mn[i];
            hC[i] = hm;
            hbuf[p ^ 1][e][j] = f2bf(hm);
        }
    };

    for (int t = 0; t < TSTEPS; t += 2) {
        step(t,     0, xA, xB);
        step(t + 1, 1, xB, xA);
    }
}

extern "C" void kernel_launch(void* const* d_in, const int* in_sizes, int n_in,
                              void* d_out, int out_size, void* d_ws, size_t ws_size,
                              hipStream_t stream) {
    const float* x    = (const float*)d_in[0];
    const float* h0   = (const float*)d_in[1];
    const float* mks  = (const float*)d_in[2];
    const float* w_ih = (const float*)d_in[3];
    const float* w_hh = (const float*)d_in[4];
    const float* b_ih = (const float*)d_in[5];
    const float* b_hh = (const float*)d_in[6];
    (void)in_sizes; (void)n_in; (void)out_size;

    if (ws_size >= GI_BYTES) {
        float* gi = (float*)d_ws;
        gi_gemm<<<dim3(128 * 16), dim3(NTHREADS), 0, stream>>>(x, w_ih, b_ih, b_hh, gi);
        gru_scan<<<dim3(NBLK), dim3(NTHREADS), 0, stream>>>(gi, h0, mks, w_hh, b_hh,
                                                            (float*)d_out);
    } else {
        gru_fused<<<dim3(NBLK), dim3(NTHREADS), 0, stream>>>(
            x, h0, mks, w_ih, w_hh, b_ih, b_hh, (float*)d_out);
    }
}

// Round 7
// 1986.850 us; speedup vs baseline: 1.6958x; 1.2002x over previous
//
#include <hip/hip_runtime.h>

#define TSTEPS 2048
#define NENV   256
#define HID    128
#define EPB    16                 // envs per block (= MFMA M/N)
#define NBLK   (NENV / EPB)       // 16 blocks for the scan
#define NTHREADS 512              // 8 waves; wave w owns h-dims [16w,16w+16)

// packed-x layout: [t][eb][kk(4)][quad(4)][l15(16)][8 bf16]  (4KB per (t,eb))
// scan lane(quad,l15) reads its B-frag at base + kk*512 elems (imm offsets).
#define XP_T_STRIDE (NBLK * 2048)                 // 32768 bf16 elems per t
#define XP_BYTES  ((size_t)TSTEPS * XP_T_STRIDE * 2)   // 134 MB

#define LOG2E 1.4426950408889634f

typedef float          floatx4  __attribute__((ext_vector_type(4)));
typedef __bf16         bf16x8   __attribute__((ext_vector_type(8)));
typedef unsigned short ushortx8 __attribute__((ext_vector_type(8)));
typedef unsigned int   uintx4   __attribute__((ext_vector_type(4)));
typedef unsigned int   uintx2   __attribute__((ext_vector_type(2)));

// fp32 -> bf16 round-to-nearest-even (scalar fallback)
__device__ __forceinline__ unsigned short f2bf(float f) {
    unsigned u = __float_as_uint(f);
    u += 0x7FFFu + ((u >> 16) & 1u);
    return (unsigned short)(u >> 16);
}

// packed fp32x2 -> bf16x2 (gfx950 v_cvt_pk_bf16_f32 when available)
__device__ __forceinline__ unsigned cvt_pk_bf16(float a, float b) {
#if __has_builtin(__builtin_amdgcn_cvt_pk_bf16_f32)
    typedef __bf16 bf16x2 __attribute__((ext_vector_type(2)));
    bf16x2 r = __builtin_amdgcn_cvt_pk_bf16_f32(a, b);
    return __builtin_bit_cast(unsigned, r);
#else
    return (unsigned)f2bf(a) | ((unsigned)f2bf(b) << 16);
#endif
}

__device__ __forceinline__ bf16x8 pack8(floatx4 a, floatx4 b) {
    uintx4 u;
    u[0] = cvt_pk_bf16(a[0], a[1]);
    u[1] = cvt_pk_bf16(a[2], a[3]);
    u[2] = cvt_pk_bf16(b[0], b[1]);
    u[3] = cvt_pk_bf16(b[2], b[3]);
    return __builtin_bit_cast(bf16x8, u);
}

__device__ __forceinline__ float fast_rcp(float x) {
#if __has_builtin(__builtin_amdgcn_rcpf)
    return __builtin_amdgcn_rcpf(x);
#else
    return 1.0f / x;
#endif
}
// raw 2^x (inputs are pre-scaled by +/-log2e at weight-pack time)
__device__ __forceinline__ float exp2_fast(float x) {
#if __has_builtin(__builtin_amdgcn_exp2f)
    return __builtin_amdgcn_exp2f(x);
#else
    float r; asm("v_exp_f32 %0, %1" : "=v"(r) : "v"(x)); return r;
#endif
}
// legacy helpers for the fused fallback kernel
__device__ __forceinline__ float sigm(float x) {
    return fast_rcp(1.0f + __expf(-x));
}
__device__ __forceinline__ float tanh_fast(float x) {
    return 1.0f - 2.0f * fast_rcp(1.0f + __expf(2.0f * x));
}

// ---------------------------------------------------------------------------
// Phase 1: pack x into bf16 MFMA B-fragments.
// Grid: TSTEPS*16 blocks x 256 threads; thread = (kk,quad,l15).
// Writes one contiguous 4KB slab per block.
// ---------------------------------------------------------------------------
__global__ __launch_bounds__(256, 4)
void x_pack(const float* __restrict__ x, unsigned short* __restrict__ xp)
{
    const int tid  = threadIdx.x;
    const int kk   = tid >> 6;
    const int quad = (tid >> 4) & 3;
    const int l15  = tid & 15;
    const int t    = blockIdx.x >> 4;
    const int eb   = blockIdx.x & 15;

    const float* xr = x + (size_t)(t * NENV + eb * EPB + l15) * HID
                        + kk * 32 + quad * 8;
    floatx4 f0 = *(const floatx4*)(xr);
    floatx4 f1 = *(const floatx4*)(xr + 4);
    bf16x8 v = pack8(f0, f1);
    *(bf16x8*)(xp + (size_t)blockIdx.x * 2048 + tid * 8) = v;
}

// ---------------------------------------------------------------------------
// Phase 2: sequential scan with fused x-side GEMM. 16 blocks x 512 threads.
// mfma(W, frag) -> C row = j, col = env: lane owns env=l15, j = jb..jb+3.
// Per step per wave: 24 MFMA (3 gates x (4 x-side + 4 h-side)), 4 xp loads
// (contiguous 1KB/wave, imm offsets), no pack VALU, vector epilogue.
// Raw s_barrier + lgkmcnt-only fence keeps global traffic in flight.
// ---------------------------------------------------------------------------
__global__ __launch_bounds__(NTHREADS, 2)
void gru_scan(const unsigned short* __restrict__ xp,
              const float* __restrict__ h0,
              const float* __restrict__ masks,
              const float* __restrict__ w_ih,
              const float* __restrict__ w_hh,
              const float* __restrict__ b_ih,
              const float* __restrict__ b_hh,
              float* __restrict__ out)
{
    __shared__ unsigned short hbuf[2][EPB][136];   // rows = env, cols = j (+8 pad)

    const int tid  = threadIdx.x;
    const int wv   = tid >> 6;
    const int lane = tid & 63;
    const int quad = lane >> 4;
    const int l15  = lane & 15;
    const int envbase = blockIdx.x * EPB;
    const int j  = wv * 16 + l15;          // weight row for A-frag
    const int jb = wv * 16 + quad * 4;     // C-row base (4 consecutive j)

    const float gscale[3] = { -LOG2E, -LOG2E, 2.0f * LOG2E };

    // A-frags: w_ih and w_hh rows, pre-scaled (96 VGPRs)
    bf16x8 bI[3][4], bH[3][4];
#pragma unroll
    for (int q = 0; q < 3; ++q) {
        const int col = q * HID + j;
        const float s = gscale[q];
#pragma unroll
        for (int kk = 0; kk < 4; ++kk) {
            const int kb = kk * 32 + quad * 8;
            floatx4 f0 = *(const floatx4*)(w_ih + col * HID + kb);
            floatx4 f1 = *(const floatx4*)(w_ih + col * HID + kb + 4);
            bI[q][kk] = pack8(f0 * s, f1 * s);
            floatx4 g0 = *(const floatx4*)(w_hh + col * HID + kb);
            floatx4 g1 = *(const floatx4*)(w_hh + col * HID + kb + 4);
            bH[q][kk] = pack8(g0 * s, g1 * s);
        }
    }
    // per-reg biases (C rows = j => bias varies across acc regs), pre-scaled
    floatx4 biasRv, biasZv, biasNIv, biasNHv;
    {
        floatx4 bi0 = *(const floatx4*)(b_ih + jb);
        floatx4 bh0 = *(const floatx4*)(b_hh + jb);
        floatx4 bi1 = *(const floatx4*)(b_ih + HID + jb);
        floatx4 bh1 = *(const floatx4*)(b_hh + HID + jb);
        floatx4 bi2 = *(const floatx4*)(b_ih + 2 * HID + jb);
        floatx4 bh2 = *(const floatx4*)(b_hh + 2 * HID + jb);
        biasRv  = (bi0 + bh0) * (-LOG2E);
        biasZv  = (bi1 + bh1) * (-LOG2E);
        biasNIv = bi2 * (2.0f * LOG2E);
        biasNHv = bh2 * (2.0f * LOG2E);
    }

    // init h (apply mask_0): lane owns env=l15, j=jb..jb+3
    float hC[4];
    {
        floatx4 h0v = *(const floatx4*)(h0 + (size_t)(envbase + l15) * HID + jb);
        float m0 = masks[envbase + l15];
#pragma unroll
        for (int i = 0; i < 4; ++i) hC[i] = h0v[i] * m0;
        uintx2 w; w[0] = cvt_pk_bf16(hC[0], hC[1]); w[1] = cvt_pk_bf16(hC[2], hC[3]);
        *(uintx2*)&hbuf[0][l15][jb] = w;
    }

    // packed-x base for this lane (same 4KB slab for all 8 waves of a block)
    const unsigned short* xbase = xp + (size_t)blockIdx.x * 2048
                                     + quad * 128 + l15 * 8;

    // depth-2 software pipeline: xA/xB = x-frags[t], [t+1]; mA/mB = mask(t+1), (t+2)
    bf16x8 xA[4], xB[4];
#pragma unroll
    for (int kk = 0; kk < 4; ++kk) {
        xA[kk] = __builtin_bit_cast(bf16x8, *(const ushortx8*)(xbase + kk * 512));
        xB[kk] = __builtin_bit_cast(bf16x8, *(const ushortx8*)(xbase + XP_T_STRIDE + kk * 512));
    }
    float mA = masks[(size_t)1 * NENV + envbase + l15];
    float mB = masks[(size_t)2 * NENV + envbase + l15];

    float* const outs = out;
    float* const hfin = out + (size_t)TSTEPS * NENV * HID;

    auto step = [&](int t, int p, bf16x8 (&xc)[4], float& mreg) {
        // hbuf[p^1] writes must be visible to all waves; LDS-only drain,
        // global loads/stores stay outstanding across the barrier.
        asm volatile("s_waitcnt lgkmcnt(0)" ::: "memory");
        __builtin_amdgcn_s_barrier();
        __builtin_amdgcn_sched_barrier(0);

        // B-frags for h from LDS (lane col = env l15, k contiguous)
        bf16x8 ah[4];
#pragma unroll
        for (int kk = 0; kk < 4; ++kk) {
            ah[kk] = __builtin_bit_cast(bf16x8,
                *(const ushortx8*)&hbuf[p][l15][kk * 32 + quad * 8]);
        }

        floatx4 accR  = biasRv;
        floatx4 accZ  = biasZv;
        floatx4 accNI = biasNIv;
        floatx4 accNH = biasNHv;

        // x-side MFMAs first (xc regs are ready; no waits)
#pragma unroll
        for (int kk = 0; kk < 4; ++kk) {
            accR  = __builtin_amdgcn_mfma_f32_16x16x32_bf16(bI[0][kk], xc[kk], accR,  0, 0, 0);
            accZ  = __builtin_amdgcn_mfma_f32_16x16x32_bf16(bI[1][kk], xc[kk], accZ,  0, 0, 0);
            accNI = __builtin_amdgcn_mfma_f32_16x16x32_bf16(bI[2][kk], xc[kk], accNI, 0, 0, 0);
        }

        // prefetch x-frags[t+2] into the same registers (~2 steps of slack)
        if (t + 2 < TSTEPS) {
            const unsigned short* xpp = xbase + (size_t)(t + 2) * XP_T_STRIDE;
#pragma unroll
            for (int kk = 0; kk < 4; ++kk)
                xc[kk] = __builtin_bit_cast(bf16x8, *(const ushortx8*)(xpp + kk * 512));
        }
        // mask(t+1) for this step's epilogue; reload mreg with mask(t+3)
        float mn = mreg;
        mreg = (t + 3 < TSTEPS)
             ? masks[(size_t)(t + 3) * NENV + envbase + l15] : 1.0f;

        // h-side MFMAs
#pragma unroll
        for (int kk = 0; kk < 4; ++kk) {
            accR  = __builtin_amdgcn_mfma_f32_16x16x32_bf16(bH[0][kk], ah[kk], accR,  0, 0, 0);
            accZ  = __builtin_amdgcn_mfma_f32_16x16x32_bf16(bH[1][kk], ah[kk], accZ,  0, 0, 0);
            accNH = __builtin_amdgcn_mfma_f32_16x16x32_bf16(bH[2][kk], ah[kk], accNH, 0, 0, 0);
        }

        floatx4 hv;
#pragma unroll
        for (int i = 0; i < 4; ++i) {
            // accR/accZ = -log2e*pre  => sigmoid = rcp(1+2^acc)
            float r    = fast_rcp(1.0f + exp2_fast(accR[i]));
            float z    = fast_rcp(1.0f + exp2_fast(accZ[i]));
            // accNI/accNH = 2log2e*pre => tanh = 1 - 2*rcp(1+2^in)
            float ti   = accNI[i] + r * accNH[i];
            float n    = 1.0f - 2.0f * fast_rcp(1.0f + exp2_fast(ti));
            float hnew = n + z * (hC[i] - n);
            hv[i] = hnew;
            hC[i] = hnew * mn;
        }
        *(floatx4*)(outs + ((size_t)t * NENV + envbase + l15) * HID + jb) = hv;
        uintx2 w; w[0] = cvt_pk_bf16(hC[0], hC[1]); w[1] = cvt_pk_bf16(hC[2], hC[3]);
        *(uintx2*)&hbuf[p ^ 1][l15][jb] = w;
    };

    for (int t = 0; t < TSTEPS; t += 2) {
        step(t,     0, xA, mA);
        step(t + 1, 1, xB, mB);
    }
    // final state: mask(2048) forced to 1.0, so hC == h_{T-1}
    floatx4 hf; hf[0] = hC[0]; hf[1] = hC[1]; hf[2] = hC[2]; hf[3] = hC[3];
    *(floatx4*)(hfin + (size_t)(envbase + l15) * HID + jb) = hf;
}

// ---------------------------------------------------------------------------
// Fallback: round-1 fused kernel (used only if ws_size < XP_BYTES)
// ---------------------------------------------------------------------------
__global__ __launch_bounds__(NTHREADS, 2)
void gru_fused(const float* __restrict__ x,
               const float* __restrict__ h0,
               const float* __restrict__ masks,
               const float* __restrict__ w_ih,
               const float* __restrict__ w_hh,
               const float* __restrict__ b_ih,
               const float* __restrict__ b_hh,
               float* __restrict__ out)
{
    __shared__ unsigned short hbuf[2][EPB][136];

    const int tid  = threadIdx.x;
    const int wv   = tid >> 6;
    const int lane = tid & 63;
    const int quad = lane >> 4;
    const int l15  = lane & 15;
    const int envbase = blockIdx.x * EPB;
    const int j = wv * 16 + l15;

    bf16x8 bI[3][4], bH[3][4];
#pragma unroll
    for (int q = 0; q < 3; ++q) {
        const int col = q * HID + j;
#pragma unroll
        for (int kk = 0; kk < 4; ++kk) {
            const int kb = kk * 32 + quad * 8;
            floatx4 f0 = *(const floatx4*)(w_ih + col * HID + kb);
            floatx4 f1 = *(const floatx4*)(w_ih + col * HID + kb + 4);
            bI[q][kk] = pack8(f0, f1);
            floatx4 g0 = *(const floatx4*)(w_hh + col * HID + kb);
            floatx4 g1 = *(const floatx4*)(w_hh + col * HID + kb + 4);
            bH[q][kk] = pack8(g0, g1);
        }
    }

    const float biasR  = b_ih[j]           + b_hh[j];
    const float biasZ  = b_ih[HID + j]     + b_hh[HID + j];
    const float biasNI = b_ih[2 * HID + j];
    const float biasNH = b_hh[2 * HID + j];

    float hC[4];
    {
        floatx4 m0 = *(const floatx4*)(masks + envbase + quad * 4);
#pragma unroll
        for (int i = 0; i < 4; ++i) {
            const int e = quad * 4 + i;
            float h = h0[(envbase + e) * HID + j] * m0[i];
            hC[i] = h;
            hbuf[0][e][j] = f2bf(h);
        }
    }

    floatx4 xA[8], xB[8];
    {
        const float* xr = x + (size_t)(envbase + l15) * HID;
#pragma unroll
        for (int kk = 0; kk < 4; ++kk) {
            const int kb = kk * 32 + quad * 8;
            xA[2 * kk]     = *(const floatx4*)(xr + kb);
            xA[2 * kk + 1] = *(const floatx4*)(xr + kb + 4);
        }
    }

    float* const outs = out;
    float* const hfin = out + (size_t)TSTEPS * NENV * HID;

    auto step = [&](int t, int p, floatx4 (&xc)[8], floatx4 (&xn)[8]) {
        __syncthreads();
        bf16x8 ah[4];
#pragma unroll
        for (int kk = 0; kk < 4; ++kk) {
            ah[kk] = __builtin_bit_cast(bf16x8,
                *(const ushortx8*)&hbuf[p][l15][kk * 32 + quad * 8]);
        }
        bf16x8 ax[4];
#pragma unroll
        for (int kk = 0; kk < 4; ++kk) ax[kk] = pack8(xc[2 * kk], xc[2 * kk + 1]);

        if (t + 1 < TSTEPS) {
            const float* xr = x + (size_t)((t + 1) * NENV + envbase + l15) * HID;
#pragma unroll
            for (int kk = 0; kk < 4; ++kk) {
                const int kb = kk * 32 + quad * 8;
                xn[2 * kk]     = *(const floatx4*)(xr + kb);
                xn[2 * kk + 1] = *(const floatx4*)(xr + kb + 4);
            }
        }
        floatx4 mn;
        if (t + 1 < TSTEPS) {
            mn = *(const floatx4*)(masks + (size_t)(t + 1) * NENV + envbase + quad * 4);
        } else {
            mn[0] = mn[1] = mn[2] = mn[3] = 1.0f;
        }

        floatx4 accR  = {biasR,  biasR,  biasR,  biasR};
        floatx4 accZ  = {biasZ,  biasZ,  biasZ,  biasZ};
        floatx4 accNI = {biasNI, biasNI, biasNI, biasNI};
        floatx4 accNH = {biasNH, biasNH, biasNH, biasNH};
#pragma unroll
        for (int kk = 0; kk < 4; ++kk) {
            accR  = __builtin_amdgcn_mfma_f32_16x16x32_bf16(ax[kk], bI[0][kk], accR,  0, 0, 0);
            accR  = __builtin_amdgcn_mfma_f32_16x16x32_bf16(ah[kk], bH[0][kk], accR,  0, 0, 0);
            accZ  = __builtin_amdgcn_mfma_f32_16x16x32_bf16(ax[kk], bI[1][kk], accZ,  0, 0, 0);
            accZ  = __builtin_amdgcn_mfma_f32_16x16x32_bf16(ah[kk], bH[1][kk], accZ,  0, 0, 0);
            accNI = __builtin_amdgcn_mfma_f32_16x16x32_bf16(ax[kk], bI[2][kk], accNI, 0, 0, 0);
            accNH = __builtin_amdgcn_mfma_f32_16x16x32_bf16(ah[kk], bH[2][kk], accNH, 0, 0, 0);
        }

#pragma unroll
        for (int i = 0; i < 4; ++i) {
            const int e = quad * 4 + i;
            float r    = sigm(accR[i]);
            float z    = sigm(accZ[i]);
            float n    = tanh_fast(accNI[i] + r * accNH[i]);
            float hnew = n + z * (hC[i] - n);
            outs[((size_t)t * NENV + envbase + e) * HID + j] = hnew;
            if (t == TSTEPS - 1) hfin[(envbase + e) * HID + j] = hnew;
            float hm = hnew * mn[i];
            hC[i] = hm;
            hbuf[p ^ 1][e][j] = f2bf(hm);
        }
    };

    for (int t = 0; t < TSTEPS; t += 2) {
        step(t,     0, xA, xB);
        step(t + 1, 1, xB, xA);
    }
}

extern "C" void kernel_launch(void* const* d_in, const int* in_sizes, int n_in,
                              void* d_out, int out_size, void* d_ws, size_t ws_size,
                              hipStream_t stream) {
    const float* x    = (const float*)d_in[0];
    const float* h0   = (const float*)d_in[1];
    const float* mks  = (const float*)d_in[2];
    const float* w_ih = (const float*)d_in[3];
    const float* w_hh = (const float*)d_in[4];
    const float* b_ih = (const float*)d_in[5];
    const float* b_hh = (const float*)d_in[6];
    (void)in_sizes; (void)n_in; (void)out_size;

    if (ws_size >= XP_BYTES) {
        unsigned short* xp = (unsigned short*)d_ws;
        x_pack<<<dim3(TSTEPS * NBLK), dim3(256), 0, stream>>>(x, xp);
        gru_scan<<<dim3(NBLK), dim3(NTHREADS), 0, stream>>>(xp, h0, mks, w_ih, w_hh,
                                                            b_ih, b_hh, (float*)d_out);
    } else {
        gru_fused<<<dim3(NBLK), dim3(NTHREADS), 0, stream>>>(
            x, h0, mks, w_ih, w_hh, b_ih, b_hh, (float*)d_out);
    }
}